// Round 8
// baseline (540.609 us; speedup 1.0000x reference)
//
#include <hip/hip_runtime.h>
#include <hip/hip_fp16.h>

#define NN 100000
#define EE 1600000
#define HH 64
#define GG 64
#define NBK 391    // buckets of 256 nodes: dst>>8
#define CAP 8192   // fixed bucket capacity (mean load 4092, max ~4400)

// ---------------- workspace layout (bytes) ----------------
// rowStart : int[NN]          @ 0
// rowLen   : int[NN]          @ 400000
// dinv     : float[NN]        @ 800000
// srcs     : int[NBK*CAP]     @ 1200000   (bucket-strided)
// u        : half[4][NN][16]  @ 14012288  (4 feature-quarter tables, 3.2MB each)
// hb       : float[NN*64]     @ 26812288
// tmp      : int[NBK*CAP]     @ 26812288  (overlaps hb; consumed before agg0)
// gsum     : float[4096]      @ 52412288
// gcnt     : float[64]        @ 52428672
// bcur     : int[NBK]         @ 52428928

static inline int cdiv_h(int a, int b) { return (a + b - 1) / b; }

// ---- partition edges into fixed-capacity buckets (98 blocks x 16384 edges) ----
__global__ __launch_bounds__(256) void bplace_kernel(const int* __restrict__ ei,
                                                     int* __restrict__ bcur,
                                                     int* __restrict__ tmp) {
    __shared__ int h[NBK];
    __shared__ int boff[NBK];
    for (int t = threadIdx.x; t < NBK; t += 256) h[t] = 0;
    __syncthreads();
    int base = blockIdx.x * 16384;
#pragma unroll 4
    for (int i = 0; i < 64; i++) {
        int e = base + i * 256 + threadIdx.x;
        if (e < EE) atomicAdd(&h[ei[EE + e] >> 8], 1);
    }
    __syncthreads();
    for (int t = threadIdx.x; t < NBK; t += 256) {
        int c = h[t];
        boff[t] = c ? (t * CAP + atomicAdd(&bcur[t], c)) : 0;
        h[t] = 0;  // reuse as running cursor
    }
    __syncthreads();
#pragma unroll 4
    for (int i = 0; i < 64; i++) {
        int e = base + i * 256 + threadIdx.x;
        if (e < EE) {
            int s0 = ei[e];
            int d = ei[EE + e];
            int b = d >> 8;
            int p = boff[b] + atomicAdd(&h[b], 1);
            tmp[p] = (s0 << 8) | (d & 255);
        }
    }
}

// ---- per-bucket counting sort: srcs (bucket-strided CSR), rowStart/Len, dinv ----
__global__ __launch_bounds__(256) void bsort_kernel(const int* __restrict__ tmp,
                                                    const int* __restrict__ bcur,
                                                    int* __restrict__ rowStart,
                                                    int* __restrict__ rowLen,
                                                    float* __restrict__ dinv,
                                                    int* __restrict__ srcs) {
    int b = blockIdx.x;
    int n0 = b << 8;
    int e0 = b * CAP;
    int e1 = e0 + bcur[b];
    int t = threadIdx.x;
    __shared__ int cnt[256];
    __shared__ int st[256];
    cnt[t] = 0;
    __syncthreads();
    for (int e = e0 + t; e < e1; e += 256) atomicAdd(&cnt[tmp[e] & 255], 1);
    __syncthreads();
    int v = cnt[t];
    st[t] = v;
    __syncthreads();
    for (int off = 1; off < 256; off <<= 1) {
        int w = (t >= off) ? st[t - off] : 0;
        __syncthreads();
        st[t] += w;
        __syncthreads();
    }
    int excl = st[t] - v;
    int n = n0 + t;
    if (n < NN) {
        rowStart[n] = e0 + excl;
        rowLen[n] = v;
        dinv[n] = rsqrtf((float)v + 1.0f);
    }
    __syncthreads();
    cnt[t] = e0 + excl;  // absolute cursor
    __syncthreads();
    for (int e = e0 + t; e < e1; e += 256) {
        int p = tmp[e];
        int pos = atomicAdd(&cnt[p & 255], 1);
        srcs[pos] = p >> 8;
    }
}

// ---- gcnt: parallel LDS histogram over sorted batch ids ----
__global__ __launch_bounds__(256) void gcnt_kernel(const int* __restrict__ batch,
                                                   float* __restrict__ gcnt) {
    __shared__ int h[GG];
    if (threadIdx.x < GG) h[threadIdx.x] = 0;
    __syncthreads();
    int n = blockIdx.x * 256 + threadIdx.x;
    if (n < NN) atomicAdd(&h[batch[n]], 1);
    __syncthreads();
    if (threadIdx.x < GG && h[threadIdx.x])
        atomicAdd(&gcnt[threadIdx.x], (float)h[threadIdx.x]);
}

// u[q][n][:] = (half) dinv[n] * (hin[n][:] @ W) quarter q
// one thread per (row, col-half); half = t>>7 is wave-uniform (W reads stay scalar)
__global__ __launch_bounds__(256) void gemm_kernel(const float* __restrict__ hin,
                                                   const float* __restrict__ Wg,
                                                   const float* __restrict__ dinv,
                                                   __half* __restrict__ u) {
    int t = threadIdx.x;
    int half = t >> 7;                   // waves 0,1 -> cols 0-31; waves 2,3 -> 32-63
    int n = blockIdx.x * 128 + (t & 127);
    if (n >= NN) return;
    const float* hr = hin + (size_t)n * 64;
    float acc[32];
#pragma unroll
    for (int j = 0; j < 32; j++) acc[j] = 0.0f;
#pragma unroll 2
    for (int k = 0; k < 64; k++) {
        float hk = hr[k];
        const float4* Wr = (const float4*)(Wg + (k << 6) + half * 32);
#pragma unroll
        for (int j = 0; j < 8; j++) {
            float4 w = Wr[j];
            acc[j * 4 + 0] = fmaf(hk, w.x, acc[j * 4 + 0]);
            acc[j * 4 + 1] = fmaf(hk, w.y, acc[j * 4 + 1]);
            acc[j * 4 + 2] = fmaf(hk, w.z, acc[j * 4 + 2]);
            acc[j * 4 + 3] = fmaf(hk, w.w, acc[j * 4 + 3]);
        }
    }
    float dv = dinv[n];
#pragma unroll
    for (int qq = 0; qq < 2; qq++) {
        int q = half * 2 + qq;
        __half2 hh[8];
#pragma unroll
        for (int j = 0; j < 8; j++)
            hh[j] = __floats2half2_rn(acc[qq * 16 + 2 * j] * dv,
                                      acc[qq * 16 + 2 * j + 1] * dv);
        float4* dst = (float4*)(u + ((size_t)q * NN + n) * 16);
        dst[0] = *(float4*)&hh[0];
        dst[1] = *(float4*)&hh[4];
    }
}

// ---- quarter gather: 2 lanes per edge-quarter, 16B loads ----
// lane = ng*16 + sub*2 + fl : ng = node (4/wave), sub = edge slot (8), fl = half-row (2).
// One wave load instruction covers 4 nodes x 8 edges x 16B = 32 edge-quarters.
__device__ __forceinline__ void add8(float4 raw, float* a) {
    const __half2* h = (const __half2*)&raw;
#pragma unroll
    for (int i = 0; i < 4; i++) {
        float2 f = __half22float2(h[i]);
        a[2 * i] += f.x;
        a[2 * i + 1] += f.y;
    }
}

__device__ __forceinline__ void gatherq8(const __half* __restrict__ uq,
                                         const int* __restrict__ srcs,
                                         int n, int sub, int fl, int rs, int len,
                                         float* a) {
#pragma unroll
    for (int i = 0; i < 8; i++) a[i] = 0.0f;
    if (sub == 0)
        add8(*(const float4*)(uq + (size_t)n * 16 + fl * 8), a);
    int e = rs + sub, end = rs + len;
    for (; e + 8 < end; e += 16) {
        int sA = srcs[e];
        int sB = srcs[e + 8];
        float4 ra = *(const float4*)(uq + (size_t)sA * 16 + fl * 8);
        float4 rb = *(const float4*)(uq + (size_t)sB * 16 + fl * 8);
        add8(ra, a);
        add8(rb, a);
    }
    if (e < end)
        add8(*(const float4*)(uq + (size_t)srcs[e] * 16 + fl * 8), a);
}

// sum over sub (lane bits 1-3)
__device__ __forceinline__ void sub_reduce8(float* a) {
#pragma unroll
    for (int m = 2; m <= 8; m <<= 1) {
#pragma unroll
        for (int i = 0; i < 8; i++) a[i] += __shfl_xor(a[i], m);
    }
}

// layers 0,1: block = 16 nodes x 1 quarter; q = blockIdx&3 (round-robin XCD
// => one 3.2MB quarter table resident per XCD L2 -- confirmed R6/R7 FETCH)
__global__ __launch_bounds__(256) void agg_kernel(const __half* __restrict__ u,
                                                  const int* __restrict__ srcs,
                                                  const int* __restrict__ rowStart,
                                                  const int* __restrict__ rowLen,
                                                  const float* __restrict__ dinv,
                                                  const float* __restrict__ bias,
                                                  float* __restrict__ hout) {
    int q = blockIdx.x & 3;
    int grp = blockIdx.x >> 2;
    int w = threadIdx.x >> 6;
    int lane = threadIdx.x & 63;
    int ng = lane >> 4;
    int sub = (lane >> 1) & 7;
    int fl = lane & 1;
    int n = grp * 16 + w * 4 + ng;  // NN divisible by 16
    const __half* uq = u + (size_t)q * NN * 16;
    int rs = rowStart[n], len = rowLen[n];
    float a[8];
    gatherq8(uq, srcs, n, sub, fl, rs, len, a);
    sub_reduce8(a);
    if (sub == 0) {
        float dv = dinv[n];
        const float4* bb = (const float4*)(bias + q * 16 + fl * 8);
        float4 b0 = bb[0], b1 = bb[1];
        float4 r0, r1;
        r0.x = fmaxf(fmaf(dv, a[0], b0.x), 0.0f);
        r0.y = fmaxf(fmaf(dv, a[1], b0.y), 0.0f);
        r0.z = fmaxf(fmaf(dv, a[2], b0.z), 0.0f);
        r0.w = fmaxf(fmaf(dv, a[3], b0.w), 0.0f);
        r1.x = fmaxf(fmaf(dv, a[4], b1.x), 0.0f);
        r1.y = fmaxf(fmaf(dv, a[5], b1.y), 0.0f);
        r1.z = fmaxf(fmaf(dv, a[6], b1.z), 0.0f);
        r1.w = fmaxf(fmaf(dv, a[7], b1.w), 0.0f);
        float4* op = (float4*)(hout + (size_t)n * 64 + q * 16 + fl * 8);
        op[0] = r0;
        op[1] = r1;
    }
}

// layer 2 fused with mean-pool partial sums (16 nodes x 1 quarter per block)
__global__ __launch_bounds__(256) void agg_pool_kernel(const __half* __restrict__ u,
                                                       const int* __restrict__ srcs,
                                                       const int* __restrict__ rowStart,
                                                       const int* __restrict__ rowLen,
                                                       const float* __restrict__ dinv,
                                                       const float* __restrict__ bias,
                                                       const int* __restrict__ batch,
                                                       float* __restrict__ gsum) {
    int q = blockIdx.x & 3;
    int grp = blockIdx.x >> 2;
    int w = threadIdx.x >> 6;
    int lane = threadIdx.x & 63;
    int ng = lane >> 4;
    int sub = (lane >> 1) & 7;
    int fl = lane & 1;
    int n = grp * 16 + w * 4 + ng;
    const __half* uq = u + (size_t)q * NN * 16;
    __shared__ float vals[16][16];
    __shared__ int gid[16];
    int rs = rowStart[n], len = rowLen[n];
    float a[8];
    gatherq8(uq, srcs, n, sub, fl, rs, len, a);
    sub_reduce8(a);
    if (sub == 0) {
        float dv = dinv[n];
        const float4* bb = (const float4*)(bias + q * 16 + fl * 8);
        float4 b0 = bb[0], b1 = bb[1];
        float4 r0, r1;
        r0.x = fmaxf(fmaf(dv, a[0], b0.x), 0.0f);
        r0.y = fmaxf(fmaf(dv, a[1], b0.y), 0.0f);
        r0.z = fmaxf(fmaf(dv, a[2], b0.z), 0.0f);
        r0.w = fmaxf(fmaf(dv, a[3], b0.w), 0.0f);
        r1.x = fmaxf(fmaf(dv, a[4], b1.x), 0.0f);
        r1.y = fmaxf(fmaf(dv, a[5], b1.y), 0.0f);
        r1.z = fmaxf(fmaf(dv, a[6], b1.z), 0.0f);
        r1.w = fmaxf(fmaf(dv, a[7], b1.w), 0.0f);
        float4* vp = (float4*)(&vals[w * 4 + ng][fl * 8]);
        vp[0] = r0;
        vp[1] = r1;
    }
    if ((lane & 15) == 0) gid[w * 4 + ng] = batch[n];
    __syncthreads();
    // batch is sorted -> nodes in block form runs of equal graph id
    if (threadIdx.x < 16) {
        int t = threadIdx.x;
        float run = vals[0][t];
        int curg = gid[0];
        for (int j = 1; j < 16; j++) {
            int gj = gid[j];
            if (gj != curg) {
                atomicAdd(&gsum[curg * 64 + q * 16 + t], run);
                curg = gj;
                run = 0.0f;
            }
            run += vals[j][t];
        }
        atomicAdd(&gsum[curg * 64 + q * 16 + t], run);
    }
}

__global__ __launch_bounds__(128) void final_kernel(const float* __restrict__ gsum,
                                                    const float* __restrict__ gcnt,
                                                    const float* __restrict__ Wlin,
                                                    const float* __restrict__ blin,
                                                    float* __restrict__ out) {
    int t = threadIdx.x;  // 128 = G*C
    int g = t >> 1;
    int c = t & 1;
    float cnt = fmaxf(gcnt[g], 1.0f);
    float s = 0.0f;
#pragma unroll
    for (int k = 0; k < 64; k++) s = fmaf(gsum[g * 64 + k], Wlin[k * 2 + c], s);
    out[t] = s / cnt + blin[c];
}

extern "C" void kernel_launch(void* const* d_in, const int* in_sizes, int n_in,
                              void* d_out, int out_size, void* d_ws, size_t ws_size,
                              hipStream_t stream) {
    const float* x     = (const float*)d_in[0];
    const int*   ei    = (const int*)d_in[1];
    const int*   batch = (const int*)d_in[2];
    const float* W0    = (const float*)d_in[3];
    const float* b0    = (const float*)d_in[4];
    const float* W1    = (const float*)d_in[5];
    const float* b1    = (const float*)d_in[6];
    const float* W2    = (const float*)d_in[7];
    const float* b2    = (const float*)d_in[8];
    const float* Wlin  = (const float*)d_in[9];
    const float* blin  = (const float*)d_in[10];
    float* out = (float*)d_out;

    char* ws = (char*)d_ws;
    int*    rowStart = (int*)(ws + 0);
    int*    rowLen   = (int*)(ws + 400000);
    float*  dinv     = (float*)(ws + 800000);
    int*    srcs     = (int*)(ws + 1200000);
    __half* u        = (__half*)(ws + 14012288);
    float*  hb       = (float*)(ws + 26812288);
    int*    tmp      = (int*)(ws + 26812288);  // overlaps hb; dead before agg0
    float*  gsum     = (float*)(ws + 52412288);
    float*  gcnt     = (float*)(ws + 52428672);
    int*    bcur     = (int*)(ws + 52428928);

    // zero gsum+gcnt+bcur (contiguous)
    hipMemsetAsync(ws + 52412288, 0, 18204, stream);

    // CSR build: fixed-capacity bucket partition -> per-bucket sort
    bplace_kernel<<<cdiv_h(EE, 16384), 256, 0, stream>>>(ei, bcur, tmp);
    bsort_kernel<<<NBK, 256, 0, stream>>>(tmp, bcur, rowStart, rowLen, dinv, srcs);
    gcnt_kernel<<<NBK, 256, 0, stream>>>(batch, gcnt);

    int gemm_blocks = cdiv_h(NN, 128);       // 782: (row x col-half) decomposition
    int agg_blocks = (NN / 16) * 4;          // 6250 node-groups x 4 feature quarters

    gemm_kernel<<<gemm_blocks, 256, 0, stream>>>(x, W0, dinv, u);
    agg_kernel<<<agg_blocks, 256, 0, stream>>>(u, srcs, rowStart, rowLen, dinv, b0, hb);
    gemm_kernel<<<gemm_blocks, 256, 0, stream>>>(hb, W1, dinv, u);
    agg_kernel<<<agg_blocks, 256, 0, stream>>>(u, srcs, rowStart, rowLen, dinv, b1, hb);
    gemm_kernel<<<gemm_blocks, 256, 0, stream>>>(hb, W2, dinv, u);
    agg_pool_kernel<<<agg_blocks, 256, 0, stream>>>(u, srcs, rowStart, rowLen, dinv, b2, batch, gsum);

    final_kernel<<<1, 128, 0, stream>>>(gsum, gcnt, Wlin, blin, out);
}

// Round 9
// 416.634 us; speedup vs baseline: 1.2976x; 1.2976x over previous
//
#include <hip/hip_runtime.h>
#include <hip/hip_fp16.h>

#define NN 100000
#define EE 1600000
#define HH 64
#define GG 64
#define NBK 391    // buckets of 256 nodes: dst>>8
#define CAP 8192   // fixed bucket capacity (mean load 4092, max ~4400)

// ---------------- workspace layout (bytes) ----------------
// rowStart : int[NN]          @ 0
// rowLen   : int[NN]          @ 400000
// dinv     : float[NN]        @ 800000
// srcs     : int[NBK*CAP]     @ 1200000   (bucket-strided)
// u        : half[4][NN][16]  @ 14012288  (4 feature-quarter tables, 3.2MB each)
// hb       : float[NN*64]     @ 26812288
// tmp      : int[NBK*CAP]     @ 26812288  (overlaps hb; consumed before agg0)
// gsum     : float[4096]      @ 52412288
// gcnt     : float[64]        @ 52428672
// bcur     : int[NBK]         @ 52428928

static inline int cdiv_h(int a, int b) { return (a + b - 1) / b; }

// ---- partition edges into fixed-capacity buckets (98 blocks x 16384 edges) ----
__global__ __launch_bounds__(256) void bplace_kernel(const int* __restrict__ ei,
                                                     int* __restrict__ bcur,
                                                     int* __restrict__ tmp) {
    __shared__ int h[NBK];
    __shared__ int boff[NBK];
    for (int t = threadIdx.x; t < NBK; t += 256) h[t] = 0;
    __syncthreads();
    int base = blockIdx.x * 16384;
#pragma unroll 4
    for (int i = 0; i < 64; i++) {
        int e = base + i * 256 + threadIdx.x;
        if (e < EE) atomicAdd(&h[ei[EE + e] >> 8], 1);
    }
    __syncthreads();
    for (int t = threadIdx.x; t < NBK; t += 256) {
        int c = h[t];
        boff[t] = c ? (t * CAP + atomicAdd(&bcur[t], c)) : 0;
        h[t] = 0;  // reuse as running cursor
    }
    __syncthreads();
#pragma unroll 4
    for (int i = 0; i < 64; i++) {
        int e = base + i * 256 + threadIdx.x;
        if (e < EE) {
            int s0 = ei[e];
            int d = ei[EE + e];
            int b = d >> 8;
            int p = boff[b] + atomicAdd(&h[b], 1);
            tmp[p] = (s0 << 8) | (d & 255);
        }
    }
}

// ---- per-bucket counting sort: srcs (bucket-strided CSR), rowStart/Len, dinv ----
__global__ __launch_bounds__(256) void bsort_kernel(const int* __restrict__ tmp,
                                                    const int* __restrict__ bcur,
                                                    int* __restrict__ rowStart,
                                                    int* __restrict__ rowLen,
                                                    float* __restrict__ dinv,
                                                    int* __restrict__ srcs) {
    int b = blockIdx.x;
    int n0 = b << 8;
    int e0 = b * CAP;
    int e1 = e0 + bcur[b];
    int t = threadIdx.x;
    __shared__ int cnt[256];
    __shared__ int st[256];
    cnt[t] = 0;
    __syncthreads();
    for (int e = e0 + t; e < e1; e += 256) atomicAdd(&cnt[tmp[e] & 255], 1);
    __syncthreads();
    int v = cnt[t];
    st[t] = v;
    __syncthreads();
    for (int off = 1; off < 256; off <<= 1) {
        int w = (t >= off) ? st[t - off] : 0;
        __syncthreads();
        st[t] += w;
        __syncthreads();
    }
    int excl = st[t] - v;
    int n = n0 + t;
    if (n < NN) {
        rowStart[n] = e0 + excl;
        rowLen[n] = v;
        dinv[n] = rsqrtf((float)v + 1.0f);
    }
    __syncthreads();
    cnt[t] = e0 + excl;  // absolute cursor
    __syncthreads();
    for (int e = e0 + t; e < e1; e += 256) {
        int p = tmp[e];
        int pos = atomicAdd(&cnt[p & 255], 1);
        srcs[pos] = p >> 8;
    }
}

// ---- gcnt: parallel LDS histogram over sorted batch ids ----
__global__ __launch_bounds__(256) void gcnt_kernel(const int* __restrict__ batch,
                                                   float* __restrict__ gcnt) {
    __shared__ int h[GG];
    if (threadIdx.x < GG) h[threadIdx.x] = 0;
    __syncthreads();
    int n = blockIdx.x * 256 + threadIdx.x;
    if (n < NN) atomicAdd(&h[batch[n]], 1);
    __syncthreads();
    if (threadIdx.x < GG && h[threadIdx.x])
        atomicAdd(&gcnt[threadIdx.x], (float)h[threadIdx.x]);
}

// u[q][n][:] = (half) dinv[n] * (hin[n][:] @ W) quarter q  -- one thread per row.
// Row loaded as 2 bursts of 8 independent float4 (deep pipeline, no per-k scalar
// load stall -- R8's 64 dependency-spaced scalar loads gave VALUBusy 6.8%).
__global__ __launch_bounds__(256) void gemm_kernel(const float* __restrict__ hin,
                                                   const float* __restrict__ Wg,
                                                   const float* __restrict__ dinv,
                                                   __half* __restrict__ u) {
    int n = blockIdx.x * 256 + threadIdx.x;
    if (n >= NN) return;
    const float4* hr4 = (const float4*)(hin + (size_t)n * 64);
    float acc[64];
#pragma unroll
    for (int j = 0; j < 64; j++) acc[j] = 0.0f;
    float4 buf[8];
#pragma unroll
    for (int i = 0; i < 8; i++) buf[i] = hr4[i];  // k = 0..31
#pragma unroll
    for (int h2 = 0; h2 < 2; h2++) {
        const float* bf = (const float*)buf;
#pragma unroll
        for (int kk = 0; kk < 32; kk++) {
            float hk = bf[kk];
            const float4* Wr = (const float4*)(Wg + ((h2 * 32 + kk) << 6));
#pragma unroll
            for (int j = 0; j < 16; j++) {
                float4 w = Wr[j];
                acc[j * 4 + 0] = fmaf(hk, w.x, acc[j * 4 + 0]);
                acc[j * 4 + 1] = fmaf(hk, w.y, acc[j * 4 + 1]);
                acc[j * 4 + 2] = fmaf(hk, w.z, acc[j * 4 + 2]);
                acc[j * 4 + 3] = fmaf(hk, w.w, acc[j * 4 + 3]);
            }
        }
        if (h2 == 0) {
#pragma unroll
            for (int i = 0; i < 8; i++) buf[i] = hr4[8 + i];  // k = 32..63
        }
    }
    float dv = dinv[n];
#pragma unroll
    for (int q = 0; q < 4; q++) {
        __half2 hh[8];
#pragma unroll
        for (int j = 0; j < 8; j++)
            hh[j] = __floats2half2_rn(acc[q * 16 + 2 * j] * dv,
                                      acc[q * 16 + 2 * j + 1] * dv);
        float4* dst = (float4*)(u + ((size_t)q * NN + n) * 16);
        dst[0] = *(float4*)&hh[0];
        dst[1] = *(float4*)&hh[4];
    }
}

// ---- quarter gather: 2 lanes per edge-quarter, 16B loads ----
// lane = ng*16 + sub*2 + fl : ng = node (4/wave), sub = edge slot (8), fl = half-row (2).
__device__ __forceinline__ void add8(float4 raw, float* a) {
    const __half2* h = (const __half2*)&raw;
#pragma unroll
    for (int i = 0; i < 4; i++) {
        float2 f = __half22float2(h[i]);
        a[2 * i] += f.x;
        a[2 * i + 1] += f.y;
    }
}

__device__ __forceinline__ void gatherq8(const __half* __restrict__ uq,
                                         const int* __restrict__ srcs,
                                         int n, int sub, int fl, int rs, int len,
                                         float* a) {
#pragma unroll
    for (int i = 0; i < 8; i++) a[i] = 0.0f;
    if (sub == 0)
        add8(*(const float4*)(uq + (size_t)n * 16 + fl * 8), a);
    int e = rs + sub, end = rs + len;
    for (; e + 8 < end; e += 16) {
        int sA = srcs[e];
        int sB = srcs[e + 8];
        float4 ra = *(const float4*)(uq + (size_t)sA * 16 + fl * 8);
        float4 rb = *(const float4*)(uq + (size_t)sB * 16 + fl * 8);
        add8(ra, a);
        add8(rb, a);
    }
    if (e < end)
        add8(*(const float4*)(uq + (size_t)srcs[e] * 16 + fl * 8), a);
}

// sum over sub (lane bits 1-3)
__device__ __forceinline__ void sub_reduce8(float* a) {
#pragma unroll
    for (int m = 2; m <= 8; m <<= 1) {
#pragma unroll
        for (int i = 0; i < 8; i++) a[i] += __shfl_xor(a[i], m);
    }
}

// layers 0,1: block = 16 nodes x 1 quarter; q = blockIdx&3 (round-robin XCD
// => one 3.2MB quarter table resident per XCD L2 -- confirmed R6/R7 FETCH)
__global__ __launch_bounds__(256) void agg_kernel(const __half* __restrict__ u,
                                                  const int* __restrict__ srcs,
                                                  const int* __restrict__ rowStart,
                                                  const int* __restrict__ rowLen,
                                                  const float* __restrict__ dinv,
                                                  const float* __restrict__ bias,
                                                  float* __restrict__ hout) {
    int q = blockIdx.x & 3;
    int grp = blockIdx.x >> 2;
    int w = threadIdx.x >> 6;
    int lane = threadIdx.x & 63;
    int ng = lane >> 4;
    int sub = (lane >> 1) & 7;
    int fl = lane & 1;
    int n = grp * 16 + w * 4 + ng;  // NN divisible by 16
    const __half* uq = u + (size_t)q * NN * 16;
    int rs = rowStart[n], len = rowLen[n];
    float a[8];
    gatherq8(uq, srcs, n, sub, fl, rs, len, a);
    sub_reduce8(a);
    if (sub == 0) {
        float dv = dinv[n];
        const float4* bb = (const float4*)(bias + q * 16 + fl * 8);
        float4 b0 = bb[0], b1 = bb[1];
        float4 r0, r1;
        r0.x = fmaxf(fmaf(dv, a[0], b0.x), 0.0f);
        r0.y = fmaxf(fmaf(dv, a[1], b0.y), 0.0f);
        r0.z = fmaxf(fmaf(dv, a[2], b0.z), 0.0f);
        r0.w = fmaxf(fmaf(dv, a[3], b0.w), 0.0f);
        r1.x = fmaxf(fmaf(dv, a[4], b1.x), 0.0f);
        r1.y = fmaxf(fmaf(dv, a[5], b1.y), 0.0f);
        r1.z = fmaxf(fmaf(dv, a[6], b1.z), 0.0f);
        r1.w = fmaxf(fmaf(dv, a[7], b1.w), 0.0f);
        float4* op = (float4*)(hout + (size_t)n * 64 + q * 16 + fl * 8);
        op[0] = r0;
        op[1] = r1;
    }
}

// layer 2 fused with mean-pool partial sums (16 nodes x 1 quarter per block)
__global__ __launch_bounds__(256) void agg_pool_kernel(const __half* __restrict__ u,
                                                       const int* __restrict__ srcs,
                                                       const int* __restrict__ rowStart,
                                                       const int* __restrict__ rowLen,
                                                       const float* __restrict__ dinv,
                                                       const float* __restrict__ bias,
                                                       const int* __restrict__ batch,
                                                       float* __restrict__ gsum) {
    int q = blockIdx.x & 3;
    int grp = blockIdx.x >> 2;
    int w = threadIdx.x >> 6;
    int lane = threadIdx.x & 63;
    int ng = lane >> 4;
    int sub = (lane >> 1) & 7;
    int fl = lane & 1;
    int n = grp * 16 + w * 4 + ng;
    const __half* uq = u + (size_t)q * NN * 16;
    __shared__ float vals[16][16];
    __shared__ int gid[16];
    int rs = rowStart[n], len = rowLen[n];
    float a[8];
    gatherq8(uq, srcs, n, sub, fl, rs, len, a);
    sub_reduce8(a);
    if (sub == 0) {
        float dv = dinv[n];
        const float4* bb = (const float4*)(bias + q * 16 + fl * 8);
        float4 b0 = bb[0], b1 = bb[1];
        float4 r0, r1;
        r0.x = fmaxf(fmaf(dv, a[0], b0.x), 0.0f);
        r0.y = fmaxf(fmaf(dv, a[1], b0.y), 0.0f);
        r0.z = fmaxf(fmaf(dv, a[2], b0.z), 0.0f);
        r0.w = fmaxf(fmaf(dv, a[3], b0.w), 0.0f);
        r1.x = fmaxf(fmaf(dv, a[4], b1.x), 0.0f);
        r1.y = fmaxf(fmaf(dv, a[5], b1.y), 0.0f);
        r1.z = fmaxf(fmaf(dv, a[6], b1.z), 0.0f);
        r1.w = fmaxf(fmaf(dv, a[7], b1.w), 0.0f);
        float4* vp = (float4*)(&vals[w * 4 + ng][fl * 8]);
        vp[0] = r0;
        vp[1] = r1;
    }
    if ((lane & 15) == 0) gid[w * 4 + ng] = batch[n];
    __syncthreads();
    // batch is sorted -> nodes in block form runs of equal graph id
    if (threadIdx.x < 16) {
        int t = threadIdx.x;
        float run = vals[0][t];
        int curg = gid[0];
        for (int j = 1; j < 16; j++) {
            int gj = gid[j];
            if (gj != curg) {
                atomicAdd(&gsum[curg * 64 + q * 16 + t], run);
                curg = gj;
                run = 0.0f;
            }
            run += vals[j][t];
        }
        atomicAdd(&gsum[curg * 64 + q * 16 + t], run);
    }
}

__global__ __launch_bounds__(128) void final_kernel(const float* __restrict__ gsum,
                                                    const float* __restrict__ gcnt,
                                                    const float* __restrict__ Wlin,
                                                    const float* __restrict__ blin,
                                                    float* __restrict__ out) {
    int t = threadIdx.x;  // 128 = G*C
    int g = t >> 1;
    int c = t & 1;
    float cnt = fmaxf(gcnt[g], 1.0f);
    float s = 0.0f;
#pragma unroll
    for (int k = 0; k < 64; k++) s = fmaf(gsum[g * 64 + k], Wlin[k * 2 + c], s);
    out[t] = s / cnt + blin[c];
}

extern "C" void kernel_launch(void* const* d_in, const int* in_sizes, int n_in,
                              void* d_out, int out_size, void* d_ws, size_t ws_size,
                              hipStream_t stream) {
    const float* x     = (const float*)d_in[0];
    const int*   ei    = (const int*)d_in[1];
    const int*   batch = (const int*)d_in[2];
    const float* W0    = (const float*)d_in[3];
    const float* b0    = (const float*)d_in[4];
    const float* W1    = (const float*)d_in[5];
    const float* b1    = (const float*)d_in[6];
    const float* W2    = (const float*)d_in[7];
    const float* b2    = (const float*)d_in[8];
    const float* Wlin  = (const float*)d_in[9];
    const float* blin  = (const float*)d_in[10];
    float* out = (float*)d_out;

    char* ws = (char*)d_ws;
    int*    rowStart = (int*)(ws + 0);
    int*    rowLen   = (int*)(ws + 400000);
    float*  dinv     = (float*)(ws + 800000);
    int*    srcs     = (int*)(ws + 1200000);
    __half* u        = (__half*)(ws + 14012288);
    float*  hb       = (float*)(ws + 26812288);
    int*    tmp      = (int*)(ws + 26812288);  // overlaps hb; dead before agg0
    float*  gsum     = (float*)(ws + 52412288);
    float*  gcnt     = (float*)(ws + 52428672);
    int*    bcur     = (int*)(ws + 52428928);

    // zero gsum+gcnt+bcur (contiguous)
    hipMemsetAsync(ws + 52412288, 0, 18204, stream);

    // CSR build: fixed-capacity bucket partition -> per-bucket sort
    bplace_kernel<<<cdiv_h(EE, 16384), 256, 0, stream>>>(ei, bcur, tmp);
    bsort_kernel<<<NBK, 256, 0, stream>>>(tmp, bcur, rowStart, rowLen, dinv, srcs);
    gcnt_kernel<<<NBK, 256, 0, stream>>>(batch, gcnt);

    int gemm_blocks = cdiv_h(NN, 256);       // 391: one thread per row
    int agg_blocks = (NN / 16) * 4;          // 6250 node-groups x 4 feature quarters

    gemm_kernel<<<gemm_blocks, 256, 0, stream>>>(x, W0, dinv, u);
    agg_kernel<<<agg_blocks, 256, 0, stream>>>(u, srcs, rowStart, rowLen, dinv, b0, hb);
    gemm_kernel<<<gemm_blocks, 256, 0, stream>>>(hb, W1, dinv, u);
    agg_kernel<<<agg_blocks, 256, 0, stream>>>(u, srcs, rowStart, rowLen, dinv, b1, hb);
    gemm_kernel<<<gemm_blocks, 256, 0, stream>>>(hb, W2, dinv, u);
    agg_pool_kernel<<<agg_blocks, 256, 0, stream>>>(u, srcs, rowStart, rowLen, dinv, b2, batch, gsum);

    final_kernel<<<1, 128, 0, stream>>>(gsum, gcnt, Wlin, blin, out);
}

// Round 10
// 381.642 us; speedup vs baseline: 1.4165x; 1.0917x over previous
//
#include <hip/hip_runtime.h>
#include <hip/hip_fp16.h>

#define NN 100000
#define EE 1600000
#define HH 64
#define GG 64
#define NBK 391    // buckets of 256 nodes: dst>>8
#define CAP 8192   // fixed bucket capacity (mean load 4092, max ~4400)

// ---------------- workspace layout (bytes) ----------------
// rowStart : int[NN]          @ 0
// rowLen   : int[NN]          @ 400000
// dinv     : float[NN]        @ 800000
// srcs     : int[NBK*CAP]     @ 1200000   (bucket-strided)
// u        : half[4][NN][16]  @ 14012288  (4 feature-quarter tables, 3.2MB each)
// hb(half) : half[NN*64]      @ 26812288
// tmp      : int[NBK*CAP]     @ 26812288  (overlaps hb; consumed before agg0)
// gsum     : float[4096]      @ 52412288
// gcnt     : float[64]        @ 52428672
// bcur     : int[NBK]         @ 52428928

static inline int cdiv_h(int a, int b) { return (a + b - 1) / b; }

// ---- partition edges into fixed-capacity buckets (391 blocks x 4096 edges) ----
// R9 ran 98 blocks -> OccupancyPercent 3.8%, 62us. 391 blocks = 4x parallelism.
__global__ __launch_bounds__(256) void bplace_kernel(const int* __restrict__ ei,
                                                     int* __restrict__ bcur,
                                                     int* __restrict__ tmp) {
    __shared__ int h[NBK];
    __shared__ int boff[NBK];
    for (int t = threadIdx.x; t < NBK; t += 256) h[t] = 0;
    __syncthreads();
    int base = blockIdx.x * 4096;
#pragma unroll 4
    for (int i = 0; i < 16; i++) {
        int e = base + i * 256 + threadIdx.x;
        if (e < EE) atomicAdd(&h[ei[EE + e] >> 8], 1);
    }
    __syncthreads();
    for (int t = threadIdx.x; t < NBK; t += 256) {
        int c = h[t];
        boff[t] = c ? (t * CAP + atomicAdd(&bcur[t], c)) : 0;
        h[t] = 0;  // reuse as running cursor
    }
    __syncthreads();
#pragma unroll 4
    for (int i = 0; i < 16; i++) {
        int e = base + i * 256 + threadIdx.x;
        if (e < EE) {
            int s0 = ei[e];
            int d = ei[EE + e];
            int b = d >> 8;
            int p = boff[b] + atomicAdd(&h[b], 1);
            tmp[p] = (s0 << 8) | (d & 255);
        }
    }
}

// ---- per-bucket counting sort: srcs (bucket-strided CSR), rowStart/Len, dinv ----
__global__ __launch_bounds__(256) void bsort_kernel(const int* __restrict__ tmp,
                                                    const int* __restrict__ bcur,
                                                    int* __restrict__ rowStart,
                                                    int* __restrict__ rowLen,
                                                    float* __restrict__ dinv,
                                                    int* __restrict__ srcs) {
    int b = blockIdx.x;
    int n0 = b << 8;
    int e0 = b * CAP;
    int e1 = e0 + bcur[b];
    int t = threadIdx.x;
    __shared__ int cnt[256];
    __shared__ int st[256];
    cnt[t] = 0;
    __syncthreads();
    for (int e = e0 + t; e < e1; e += 256) atomicAdd(&cnt[tmp[e] & 255], 1);
    __syncthreads();
    int v = cnt[t];
    st[t] = v;
    __syncthreads();
    for (int off = 1; off < 256; off <<= 1) {
        int w = (t >= off) ? st[t - off] : 0;
        __syncthreads();
        st[t] += w;
        __syncthreads();
    }
    int excl = st[t] - v;
    int n = n0 + t;
    if (n < NN) {
        rowStart[n] = e0 + excl;
        rowLen[n] = v;
        dinv[n] = rsqrtf((float)v + 1.0f);
    }
    __syncthreads();
    cnt[t] = e0 + excl;  // absolute cursor
    __syncthreads();
    for (int e = e0 + t; e < e1; e += 256) {
        int p = tmp[e];
        int pos = atomicAdd(&cnt[p & 255], 1);
        srcs[pos] = p >> 8;
    }
}

// ---- gcnt: parallel LDS histogram over sorted batch ids ----
__global__ __launch_bounds__(256) void gcnt_kernel(const int* __restrict__ batch,
                                                   float* __restrict__ gcnt) {
    __shared__ int h[GG];
    if (threadIdx.x < GG) h[threadIdx.x] = 0;
    __syncthreads();
    int n = blockIdx.x * 256 + threadIdx.x;
    if (n < NN) atomicAdd(&h[batch[n]], 1);
    __syncthreads();
    if (threadIdx.x < GG && h[threadIdx.x])
        atomicAdd(&gcnt[threadIdx.x], (float)h[threadIdx.x]);
}

// ---- gemm epilogue shared: write u quarters ----
__device__ __forceinline__ void write_u(float* acc, float dv, int n, __half* u) {
#pragma unroll
    for (int q = 0; q < 4; q++) {
        __half2 hh[8];
#pragma unroll
        for (int j = 0; j < 8; j++)
            hh[j] = __floats2half2_rn(acc[q * 16 + 2 * j] * dv,
                                      acc[q * 16 + 2 * j + 1] * dv);
        float4* dst = (float4*)(u + ((size_t)q * NN + n) * 16);
        dst[0] = *(float4*)&hh[0];
        dst[1] = *(float4*)&hh[4];
    }
}

// layer 0: fp32 input rows (x). Burst row loads (R9 fix: no per-k scalar stall).
__global__ __launch_bounds__(256) void gemm_f32_kernel(const float* __restrict__ hin,
                                                       const float* __restrict__ Wg,
                                                       const float* __restrict__ dinv,
                                                       __half* __restrict__ u) {
    int n = blockIdx.x * 256 + threadIdx.x;
    if (n >= NN) return;
    const float4* hr4 = (const float4*)(hin + (size_t)n * 64);
    float acc[64];
#pragma unroll
    for (int j = 0; j < 64; j++) acc[j] = 0.0f;
    float4 buf[8];
#pragma unroll
    for (int i = 0; i < 8; i++) buf[i] = hr4[i];
#pragma unroll
    for (int h2 = 0; h2 < 2; h2++) {
        const float* bf = (const float*)buf;
#pragma unroll
        for (int kk = 0; kk < 32; kk++) {
            float hk = bf[kk];
            const float4* Wr = (const float4*)(Wg + ((h2 * 32 + kk) << 6));
#pragma unroll
            for (int j = 0; j < 16; j++) {
                float4 w = Wr[j];
                acc[j * 4 + 0] = fmaf(hk, w.x, acc[j * 4 + 0]);
                acc[j * 4 + 1] = fmaf(hk, w.y, acc[j * 4 + 1]);
                acc[j * 4 + 2] = fmaf(hk, w.z, acc[j * 4 + 2]);
                acc[j * 4 + 3] = fmaf(hk, w.w, acc[j * 4 + 3]);
            }
        }
        if (h2 == 0) {
#pragma unroll
            for (int i = 0; i < 8; i++) buf[i] = hr4[8 + i];
        }
    }
    write_u(acc, dinv[n], n, u);
}

// layers 1,2: fp16 input rows (hb) -- half the input stream of fp32
__global__ __launch_bounds__(256) void gemm_f16_kernel(const __half* __restrict__ hin,
                                                       const float* __restrict__ Wg,
                                                       const float* __restrict__ dinv,
                                                       __half* __restrict__ u) {
    int n = blockIdx.x * 256 + threadIdx.x;
    if (n >= NN) return;
    const float4* hr4 = (const float4*)(hin + (size_t)n * 64);  // 8 x 16B = 64 halfs
    float acc[64];
#pragma unroll
    for (int j = 0; j < 64; j++) acc[j] = 0.0f;
    float4 raw[4];
#pragma unroll
    for (int i = 0; i < 4; i++) raw[i] = hr4[i];  // halfs 0..31
#pragma unroll
    for (int h2 = 0; h2 < 2; h2++) {
        float bf[32];
        const __half2* hh = (const __half2*)raw;
#pragma unroll
        for (int j = 0; j < 16; j++) {
            float2 f = __half22float2(hh[j]);
            bf[2 * j] = f.x;
            bf[2 * j + 1] = f.y;
        }
        if (h2 == 0) {
#pragma unroll
            for (int i = 0; i < 4; i++) raw[i] = hr4[4 + i];  // halfs 32..63
        }
#pragma unroll
        for (int kk = 0; kk < 32; kk++) {
            float hk = bf[kk];
            const float4* Wr = (const float4*)(Wg + ((h2 * 32 + kk) << 6));
#pragma unroll
            for (int j = 0; j < 16; j++) {
                float4 w = Wr[j];
                acc[j * 4 + 0] = fmaf(hk, w.x, acc[j * 4 + 0]);
                acc[j * 4 + 1] = fmaf(hk, w.y, acc[j * 4 + 1]);
                acc[j * 4 + 2] = fmaf(hk, w.z, acc[j * 4 + 2]);
                acc[j * 4 + 3] = fmaf(hk, w.w, acc[j * 4 + 3]);
            }
        }
    }
    write_u(acc, dinv[n], n, u);
}

// ---- quarter gather: 2 lanes per edge-quarter, 16B loads, 8 nodes per wave ----
// lane = ng*8 + sub*2 + fl : ng = node (8/wave), sub = edge slot (4), fl = half-row (2).
__device__ __forceinline__ void add8(float4 raw, float* a) {
    const __half2* h = (const __half2*)&raw;
#pragma unroll
    for (int i = 0; i < 4; i++) {
        float2 f = __half22float2(h[i]);
        a[2 * i] += f.x;
        a[2 * i + 1] += f.y;
    }
}

__device__ __forceinline__ void gatherq8(const __half* __restrict__ uq,
                                         const int* __restrict__ srcs,
                                         int n, int sub, int fl, int rs, int len,
                                         float* a) {
#pragma unroll
    for (int i = 0; i < 8; i++) a[i] = 0.0f;
    if (sub == 0)
        add8(*(const float4*)(uq + (size_t)n * 16 + fl * 8), a);
    int e = rs + sub, end = rs + len;
    for (; e + 4 < end; e += 8) {
        int sA = srcs[e];
        int sB = srcs[e + 4];
        float4 ra = *(const float4*)(uq + (size_t)sA * 16 + fl * 8);
        float4 rb = *(const float4*)(uq + (size_t)sB * 16 + fl * 8);
        add8(ra, a);
        add8(rb, a);
    }
    if (e < end)
        add8(*(const float4*)(uq + (size_t)srcs[e] * 16 + fl * 8), a);
}

// sum over sub (lane bits 1-2)
__device__ __forceinline__ void sub_reduce8(float* a) {
#pragma unroll
    for (int m = 2; m <= 4; m <<= 1) {
#pragma unroll
        for (int i = 0; i < 8; i++) a[i] += __shfl_xor(a[i], m);
    }
}

__device__ __forceinline__ void relu_bias8(const float* a, float dv,
                                           const float* bias_p, float* r) {
    const float4* bb = (const float4*)bias_p;
    float4 b0 = bb[0], b1 = bb[1];
    r[0] = fmaxf(fmaf(dv, a[0], b0.x), 0.0f);
    r[1] = fmaxf(fmaf(dv, a[1], b0.y), 0.0f);
    r[2] = fmaxf(fmaf(dv, a[2], b0.z), 0.0f);
    r[3] = fmaxf(fmaf(dv, a[3], b0.w), 0.0f);
    r[4] = fmaxf(fmaf(dv, a[4], b1.x), 0.0f);
    r[5] = fmaxf(fmaf(dv, a[5], b1.y), 0.0f);
    r[6] = fmaxf(fmaf(dv, a[6], b1.z), 0.0f);
    r[7] = fmaxf(fmaf(dv, a[7], b1.w), 0.0f);
}

// layers 0,1: block = 32 nodes x 1 quarter; q = blockIdx&3 (round-robin XCD
// => one 3.2MB quarter table resident per XCD L2 -- confirmed R6/R7/R9 FETCH).
// Output hb is fp16.
__global__ __launch_bounds__(256) void agg_kernel(const __half* __restrict__ u,
                                                  const int* __restrict__ srcs,
                                                  const int* __restrict__ rowStart,
                                                  const int* __restrict__ rowLen,
                                                  const float* __restrict__ dinv,
                                                  const float* __restrict__ bias,
                                                  __half* __restrict__ hout) {
    int q = blockIdx.x & 3;
    int grp = blockIdx.x >> 2;
    int w = threadIdx.x >> 6;
    int lane = threadIdx.x & 63;
    int ng = lane >> 3;
    int sub = (lane >> 1) & 3;
    int fl = lane & 1;
    int n = grp * 32 + w * 8 + ng;  // NN divisible by 32? 100000/32 = 3125 ✓
    const __half* uq = u + (size_t)q * NN * 16;
    int rs = rowStart[n], len = rowLen[n];
    float a[8];
    gatherq8(uq, srcs, n, sub, fl, rs, len, a);
    sub_reduce8(a);
    if (sub == 0) {
        float r[8];
        relu_bias8(a, dinv[n], bias + q * 16 + fl * 8, r);
        __half2 hh[4];
#pragma unroll
        for (int i = 0; i < 4; i++) hh[i] = __floats2half2_rn(r[2 * i], r[2 * i + 1]);
        *(float4*)(hout + (size_t)n * 64 + q * 16 + fl * 8) = *(float4*)hh;
    }
}

// layer 2 fused with mean-pool partial sums (32 nodes x 1 quarter per block)
__global__ __launch_bounds__(256) void agg_pool_kernel(const __half* __restrict__ u,
                                                       const int* __restrict__ srcs,
                                                       const int* __restrict__ rowStart,
                                                       const int* __restrict__ rowLen,
                                                       const float* __restrict__ dinv,
                                                       const float* __restrict__ bias,
                                                       const int* __restrict__ batch,
                                                       float* __restrict__ gsum) {
    int q = blockIdx.x & 3;
    int grp = blockIdx.x >> 2;
    int w = threadIdx.x >> 6;
    int lane = threadIdx.x & 63;
    int ng = lane >> 3;
    int sub = (lane >> 1) & 3;
    int fl = lane & 1;
    int n = grp * 32 + w * 8 + ng;
    const __half* uq = u + (size_t)q * NN * 16;
    __shared__ float vals[32][16];
    __shared__ int gid[32];
    int rs = rowStart[n], len = rowLen[n];
    float a[8];
    gatherq8(uq, srcs, n, sub, fl, rs, len, a);
    sub_reduce8(a);
    if (sub == 0) {
        float r[8];
        relu_bias8(a, dinv[n], bias + q * 16 + fl * 8, r);
        float4* vp = (float4*)(&vals[w * 8 + ng][fl * 8]);
        vp[0] = make_float4(r[0], r[1], r[2], r[3]);
        vp[1] = make_float4(r[4], r[5], r[6], r[7]);
    }
    if ((lane & 7) == 0) gid[w * 8 + ng] = batch[n];
    __syncthreads();
    // batch is sorted -> nodes in block form runs of equal graph id
    if (threadIdx.x < 16) {
        int t = threadIdx.x;
        float run = vals[0][t];
        int curg = gid[0];
        for (int j = 1; j < 32; j++) {
            int gj = gid[j];
            if (gj != curg) {
                atomicAdd(&gsum[curg * 64 + q * 16 + t], run);
                curg = gj;
                run = 0.0f;
            }
            run += vals[j][t];
        }
        atomicAdd(&gsum[curg * 64 + q * 16 + t], run);
    }
}

__global__ __launch_bounds__(128) void final_kernel(const float* __restrict__ gsum,
                                                    const float* __restrict__ gcnt,
                                                    const float* __restrict__ Wlin,
                                                    const float* __restrict__ blin,
                                                    float* __restrict__ out) {
    int t = threadIdx.x;  // 128 = G*C
    int g = t >> 1;
    int c = t & 1;
    float cnt = fmaxf(gcnt[g], 1.0f);
    float s = 0.0f;
#pragma unroll
    for (int k = 0; k < 64; k++) s = fmaf(gsum[g * 64 + k], Wlin[k * 2 + c], s);
    out[t] = s / cnt + blin[c];
}

extern "C" void kernel_launch(void* const* d_in, const int* in_sizes, int n_in,
                              void* d_out, int out_size, void* d_ws, size_t ws_size,
                              hipStream_t stream) {
    const float* x     = (const float*)d_in[0];
    const int*   ei    = (const int*)d_in[1];
    const int*   batch = (const int*)d_in[2];
    const float* W0    = (const float*)d_in[3];
    const float* b0    = (const float*)d_in[4];
    const float* W1    = (const float*)d_in[5];
    const float* b1    = (const float*)d_in[6];
    const float* W2    = (const float*)d_in[7];
    const float* b2    = (const float*)d_in[8];
    const float* Wlin  = (const float*)d_in[9];
    const float* blin  = (const float*)d_in[10];
    float* out = (float*)d_out;

    char* ws = (char*)d_ws;
    int*    rowStart = (int*)(ws + 0);
    int*    rowLen   = (int*)(ws + 400000);
    float*  dinv     = (float*)(ws + 800000);
    int*    srcs     = (int*)(ws + 1200000);
    __half* u        = (__half*)(ws + 14012288);
    __half* hb       = (__half*)(ws + 26812288);
    int*    tmp      = (int*)(ws + 26812288);  // overlaps hb; dead before agg0
    float*  gsum     = (float*)(ws + 52412288);
    float*  gcnt     = (float*)(ws + 52428672);
    int*    bcur     = (int*)(ws + 52428928);

    // zero gsum+gcnt+bcur (contiguous)
    hipMemsetAsync(ws + 52412288, 0, 18204, stream);

    // CSR build: fixed-capacity bucket partition -> per-bucket sort
    bplace_kernel<<<cdiv_h(EE, 4096), 256, 0, stream>>>(ei, bcur, tmp);
    bsort_kernel<<<NBK, 256, 0, stream>>>(tmp, bcur, rowStart, rowLen, dinv, srcs);
    gcnt_kernel<<<NBK, 256, 0, stream>>>(batch, gcnt);

    int gemm_blocks = cdiv_h(NN, 256);       // 391: one thread per row
    int agg_blocks = (NN / 32) * 4;          // 3125 node-groups x 4 feature quarters

    gemm_f32_kernel<<<gemm_blocks, 256, 0, stream>>>(x, W0, dinv, u);
    agg_kernel<<<agg_blocks, 256, 0, stream>>>(u, srcs, rowStart, rowLen, dinv, b0, hb);
    gemm_f16_kernel<<<gemm_blocks, 256, 0, stream>>>(hb, W1, dinv, u);
    agg_kernel<<<agg_blocks, 256, 0, stream>>>(u, srcs, rowStart, rowLen, dinv, b1, hb);
    gemm_f16_kernel<<<gemm_blocks, 256, 0, stream>>>(hb, W2, dinv, u);
    agg_pool_kernel<<<agg_blocks, 256, 0, stream>>>(u, srcs, rowStart, rowLen, dinv, b2, batch, gsum);

    final_kernel<<<1, 128, 0, stream>>>(gsum, gcnt, Wlin, blin, out);
}

// Round 12
// 316.834 us; speedup vs baseline: 1.7063x; 1.2045x over previous
//
#include <hip/hip_runtime.h>
#include <hip/hip_fp16.h>

#define NN 100000
#define EE 1600000
#define HH 64
#define GG 64
#define NBK 391    // buckets of 256 nodes: dst>>8
#define CAP 8192   // fixed bucket capacity (mean load 4092, max ~4400)

typedef _Float16 f16x8 __attribute__((ext_vector_type(8)));
typedef _Float16 f16x4 __attribute__((ext_vector_type(4)));
typedef float f32x4 __attribute__((ext_vector_type(4)));

// ---------------- workspace layout (bytes) ----------------
// rowStart : int[NN]          @ 0
// rowLen   : int[NN]          @ 400000
// dinv     : float[NN]        @ 800000
// srcs     : int[NBK*CAP]     @ 1200000   (ends 14012288)
// u        : half[4][NN][16]  @ 14012288  (ends 26812288)
// hb(half) : half[NN*64]      @ 26812288  (ends 39612288)
// tmp      : int[NBK*CAP]     @ 26812288  (overlaps hb; dead before agg0; ends 39624576)
// x16      : half[NN*64]      @ 39624576  (ends 52424576)
// Wh       : half[3][16384]   @ 52424576  (32KB/layer! ends 52522880)
// gsum     : float[4096]      @ 52522880  (ends 52539264)
// gcnt     : float[64]        @ 52539264  (ends 52539520)
// bcur     : int[NBK]         @ 52539520  (ends 52541084)
// R11 crashed: gsum/bcur were placed INSIDE Wh (16KB vs 32KB/layer sizing bug)
// -> wswz clobbered bcur -> wild tmp[p] writes -> device fault.

static inline int cdiv_h(int a, int b) { return (a + b - 1) / b; }

// ---- partition edges into fixed-capacity buckets (391 blocks x 4096 edges) ----
__global__ __launch_bounds__(256) void bplace_kernel(const int* __restrict__ ei,
                                                     int* __restrict__ bcur,
                                                     int* __restrict__ tmp) {
    __shared__ int h[NBK];
    __shared__ int boff[NBK];
    for (int t = threadIdx.x; t < NBK; t += 256) h[t] = 0;
    __syncthreads();
    int base = blockIdx.x * 4096;
#pragma unroll 4
    for (int i = 0; i < 16; i++) {
        int e = base + i * 256 + threadIdx.x;
        if (e < EE) atomicAdd(&h[ei[EE + e] >> 8], 1);
    }
    __syncthreads();
    for (int t = threadIdx.x; t < NBK; t += 256) {
        int c = h[t];
        boff[t] = c ? (t * CAP + atomicAdd(&bcur[t], c)) : 0;
        h[t] = 0;  // reuse as running cursor
    }
    __syncthreads();
#pragma unroll 4
    for (int i = 0; i < 16; i++) {
        int e = base + i * 256 + threadIdx.x;
        if (e < EE) {
            int s0 = ei[e];
            int d = ei[EE + e];
            int b = d >> 8;
            int p = boff[b] + atomicAdd(&h[b], 1);
            tmp[p] = (s0 << 8) | (d & 255);
        }
    }
}

// ---- per-bucket counting sort: srcs (bucket-strided CSR), rowStart/Len, dinv ----
__global__ __launch_bounds__(256) void bsort_kernel(const int* __restrict__ tmp,
                                                    const int* __restrict__ bcur,
                                                    int* __restrict__ rowStart,
                                                    int* __restrict__ rowLen,
                                                    float* __restrict__ dinv,
                                                    int* __restrict__ srcs) {
    int b = blockIdx.x;
    int n0 = b << 8;
    int e0 = b * CAP;
    int e1 = e0 + bcur[b];
    int t = threadIdx.x;
    __shared__ int cnt[256];
    __shared__ int st[256];
    cnt[t] = 0;
    __syncthreads();
    for (int e = e0 + t; e < e1; e += 256) atomicAdd(&cnt[tmp[e] & 255], 1);
    __syncthreads();
    int v = cnt[t];
    st[t] = v;
    __syncthreads();
    for (int off = 1; off < 256; off <<= 1) {
        int w = (t >= off) ? st[t - off] : 0;
        __syncthreads();
        st[t] += w;
        __syncthreads();
    }
    int excl = st[t] - v;
    int n = n0 + t;
    if (n < NN) {
        rowStart[n] = e0 + excl;
        rowLen[n] = v;
        dinv[n] = rsqrtf((float)v + 1.0f);
    }
    __syncthreads();
    cnt[t] = e0 + excl;  // absolute cursor
    __syncthreads();
    for (int e = e0 + t; e < e1; e += 256) {
        int p = tmp[e];
        int pos = atomicAdd(&cnt[p & 255], 1);
        srcs[pos] = p >> 8;
    }
}

// ---- gcnt: parallel LDS histogram over sorted batch ids ----
__global__ __launch_bounds__(256) void gcnt_kernel(const int* __restrict__ batch,
                                                   float* __restrict__ gcnt) {
    __shared__ int h[GG];
    if (threadIdx.x < GG) h[threadIdx.x] = 0;
    __syncthreads();
    int n = blockIdx.x * 256 + threadIdx.x;
    if (n < NN) atomicAdd(&h[batch[n]], 1);
    __syncthreads();
    if (threadIdx.x < GG && h[threadIdx.x])
        atomicAdd(&gcnt[threadIdx.x], (float)h[threadIdx.x]);
}

// ---- cast x (fp32) -> x16 (fp16) ----
__global__ __launch_bounds__(256) void cast_kernel(const float* __restrict__ x,
                                                   _Float16* __restrict__ x16) {
    int i = blockIdx.x * 256 + threadIdx.x;  // one float4 per thread
    if (i >= NN * 16) return;
    float4 v = ((const float4*)x)[i];
    f16x4 o = {(_Float16)v.x, (_Float16)v.y, (_Float16)v.z, (_Float16)v.w};
    ((f16x4*)x16)[i] = o;
}

// ---- swizzle W (fp32 row-major [k][n]) into MFMA B-frag order, hi/lo fp16 ----
// B-frag for mfma_f32_16x16x32_f16: lane holds B[k=(lane>>4)*8+j][n=lane&15].
// Table per layer: frag = (t*2+h)*2+p, offset = (frag*64+lane)*8+j. 32KB/layer.
__global__ __launch_bounds__(256) void wswz_kernel(const float* __restrict__ W0,
                                                   const float* __restrict__ W1,
                                                   const float* __restrict__ W2,
                                                   _Float16* __restrict__ Wh) {
    const float* Wl = (blockIdx.x == 0) ? W0 : (blockIdx.x == 1) ? W1 : W2;
    _Float16* out = Wh + blockIdx.x * 16384;
    for (int c = threadIdx.x; c < 512; c += 256) {  // t(4) x h(2) x lane(64)
        int t = c >> 7;
        int h = (c >> 6) & 1;
        int lane = c & 63;
        int quad = lane >> 4;
        int n = lane & 15;
#pragma unroll
        for (int j = 0; j < 8; j++) {
            int k = h * 32 + quad * 8 + j;
            float w = Wl[k * 64 + t * 16 + n];
            _Float16 hi = (_Float16)w;
            _Float16 lo = (_Float16)(w - (float)hi);
            out[(((t * 2 + h) * 2 + 0) * 64 + lane) * 8 + j] = hi;
            out[(((t * 2 + h) * 2 + 1) * 64 + lane) * 8 + j] = lo;
        }
    }
}

// ---- MFMA gemm: u[q][n][:] = (half) dinv[n] * (hin[n][:] @ W) ----
// Wave = 16 rows. A[m=lane&15][k=quad*8+j] = one 16B load per k-half [m120 layout].
// W hi/lo split keeps W exact (residual MFMA); only h's fp16 quantization remains.
__global__ __launch_bounds__(256) void gemm_mfma_kernel(const _Float16* __restrict__ hin,
                                                        const _Float16* __restrict__ Whl,
                                                        const float* __restrict__ dinv,
                                                        _Float16* __restrict__ u) {
    int wid = blockIdx.x * 4 + (threadIdx.x >> 6);
    if (wid >= NN / 16) return;
    int lane = threadIdx.x & 63;
    int m = lane & 15;
    int quad = lane >> 4;
    int n0 = wid * 16;

    f16x8 a0 = *(const f16x8*)(hin + (size_t)(n0 + m) * 64 + quad * 8);
    f16x8 a1 = *(const f16x8*)(hin + (size_t)(n0 + m) * 64 + 32 + quad * 8);

    f32x4 acc[4];
#pragma unroll
    for (int t = 0; t < 4; t++) acc[t] = (f32x4){0.f, 0.f, 0.f, 0.f};

#pragma unroll
    for (int t = 0; t < 4; t++) {
        f16x8 bh0 = *(const f16x8*)(Whl + (((t * 2 + 0) * 2 + 0) * 64 + lane) * 8);
        f16x8 bl0 = *(const f16x8*)(Whl + (((t * 2 + 0) * 2 + 1) * 64 + lane) * 8);
        f16x8 bh1 = *(const f16x8*)(Whl + (((t * 2 + 1) * 2 + 0) * 64 + lane) * 8);
        f16x8 bl1 = *(const f16x8*)(Whl + (((t * 2 + 1) * 2 + 1) * 64 + lane) * 8);
        acc[t] = __builtin_amdgcn_mfma_f32_16x16x32_f16(a0, bh0, acc[t], 0, 0, 0);
        acc[t] = __builtin_amdgcn_mfma_f32_16x16x32_f16(a0, bl0, acc[t], 0, 0, 0);
        acc[t] = __builtin_amdgcn_mfma_f32_16x16x32_f16(a1, bh1, acc[t], 0, 0, 0);
        acc[t] = __builtin_amdgcn_mfma_f32_16x16x32_f16(a1, bl1, acc[t], 0, 0, 0);
    }

    // D layout: col = lane&15 (= m), row = quad*4 + reg  [m89/m91 measured]
    float4 dv4 = *(const float4*)(dinv + n0 + quad * 4);
    const float* dvp = (const float*)&dv4;
#pragma unroll
    for (int t = 0; t < 4; t++) {
#pragma unroll
        for (int i = 0; i < 4; i++) {
            int n = n0 + quad * 4 + i;
            u[((size_t)t * NN + n) * 16 + m] = (_Float16)(acc[t][i] * dvp[i]);
        }
    }
}

// ---- quarter gather: 2 lanes per edge-quarter, 16B loads, 8 nodes per wave ----
// lane = ng*8 + sub*2 + fl : ng = node (8/wave), sub = edge slot (4), fl = half-row.
__device__ __forceinline__ void add8(float4 raw, float* a) {
    const __half2* h = (const __half2*)&raw;
#pragma unroll
    for (int i = 0; i < 4; i++) {
        float2 f = __half22float2(h[i]);
        a[2 * i] += f.x;
        a[2 * i + 1] += f.y;
    }
}

__device__ __forceinline__ void gatherq8(const __half* __restrict__ uq,
                                         const int* __restrict__ srcs,
                                         int n, int sub, int fl, int rs, int len,
                                         float* a) {
#pragma unroll
    for (int i = 0; i < 8; i++) a[i] = 0.0f;
    if (sub == 0)
        add8(*(const float4*)(uq + (size_t)n * 16 + fl * 8), a);
    int e = rs + sub, end = rs + len;
    for (; e + 4 < end; e += 8) {
        int sA = srcs[e];
        int sB = srcs[e + 4];
        float4 ra = *(const float4*)(uq + (size_t)sA * 16 + fl * 8);
        float4 rb = *(const float4*)(uq + (size_t)sB * 16 + fl * 8);
        add8(ra, a);
        add8(rb, a);
    }
    if (e < end)
        add8(*(const float4*)(uq + (size_t)srcs[e] * 16 + fl * 8), a);
}

__device__ __forceinline__ void sub_reduce8(float* a) {
#pragma unroll
    for (int m = 2; m <= 4; m <<= 1) {
#pragma unroll
        for (int i = 0; i < 8; i++) a[i] += __shfl_xor(a[i], m);
    }
}

__device__ __forceinline__ void relu_bias8(const float* a, float dv,
                                           const float* bias_p, float* r) {
    const float4* bb = (const float4*)bias_p;
    float4 b0 = bb[0], b1 = bb[1];
    r[0] = fmaxf(fmaf(dv, a[0], b0.x), 0.0f);
    r[1] = fmaxf(fmaf(dv, a[1], b0.y), 0.0f);
    r[2] = fmaxf(fmaf(dv, a[2], b0.z), 0.0f);
    r[3] = fmaxf(fmaf(dv, a[3], b0.w), 0.0f);
    r[4] = fmaxf(fmaf(dv, a[4], b1.x), 0.0f);
    r[5] = fmaxf(fmaf(dv, a[5], b1.y), 0.0f);
    r[6] = fmaxf(fmaf(dv, a[6], b1.z), 0.0f);
    r[7] = fmaxf(fmaf(dv, a[7], b1.w), 0.0f);
}

// layers 0,1: block = 32 nodes x 1 quarter; q = blockIdx&3 (round-robin XCD =>
// one 3.2MB quarter table per XCD L2 -- confirmed R6/R7/R9/R10 FETCH). fp16 out.
__global__ __launch_bounds__(256) void agg_kernel(const __half* __restrict__ u,
                                                  const int* __restrict__ srcs,
                                                  const int* __restrict__ rowStart,
                                                  const int* __restrict__ rowLen,
                                                  const float* __restrict__ dinv,
                                                  const float* __restrict__ bias,
                                                  __half* __restrict__ hout) {
    int q = blockIdx.x & 3;
    int grp = blockIdx.x >> 2;
    int w = threadIdx.x >> 6;
    int lane = threadIdx.x & 63;
    int ng = lane >> 3;
    int sub = (lane >> 1) & 3;
    int fl = lane & 1;
    int n = grp * 32 + w * 8 + ng;
    const __half* uq = u + (size_t)q * NN * 16;
    int rs = rowStart[n], len = rowLen[n];
    float a[8];
    gatherq8(uq, srcs, n, sub, fl, rs, len, a);
    sub_reduce8(a);
    if (sub == 0) {
        float r[8];
        relu_bias8(a, dinv[n], bias + q * 16 + fl * 8, r);
        __half2 hh[4];
#pragma unroll
        for (int i = 0; i < 4; i++) hh[i] = __floats2half2_rn(r[2 * i], r[2 * i + 1]);
        *(float4*)(hout + (size_t)n * 64 + q * 16 + fl * 8) = *(float4*)hh;
    }
}

// layer 2 fused with mean-pool partial sums (32 nodes x 1 quarter per block)
__global__ __launch_bounds__(256) void agg_pool_kernel(const __half* __restrict__ u,
                                                       const int* __restrict__ srcs,
                                                       const int* __restrict__ rowStart,
                                                       const int* __restrict__ rowLen,
                                                       const float* __restrict__ dinv,
                                                       const float* __restrict__ bias,
                                                       const int* __restrict__ batch,
                                                       float* __restrict__ gsum) {
    int q = blockIdx.x & 3;
    int grp = blockIdx.x >> 2;
    int w = threadIdx.x >> 6;
    int lane = threadIdx.x & 63;
    int ng = lane >> 3;
    int sub = (lane >> 1) & 3;
    int fl = lane & 1;
    int n = grp * 32 + w * 8 + ng;
    const __half* uq = u + (size_t)q * NN * 16;
    __shared__ float vals[32][16];
    __shared__ int gid[32];
    int rs = rowStart[n], len = rowLen[n];
    float a[8];
    gatherq8(uq, srcs, n, sub, fl, rs, len, a);
    sub_reduce8(a);
    if (sub == 0) {
        float r[8];
        relu_bias8(a, dinv[n], bias + q * 16 + fl * 8, r);
        float4* vp = (float4*)(&vals[w * 8 + ng][fl * 8]);
        vp[0] = make_float4(r[0], r[1], r[2], r[3]);
        vp[1] = make_float4(r[4], r[5], r[6], r[7]);
    }
    if ((lane & 7) == 0) gid[w * 8 + ng] = batch[n];
    __syncthreads();
    if (threadIdx.x < 16) {
        int t = threadIdx.x;
        float run = vals[0][t];
        int curg = gid[0];
        for (int j = 1; j < 32; j++) {
            int gj = gid[j];
            if (gj != curg) {
                atomicAdd(&gsum[curg * 64 + q * 16 + t], run);
                curg = gj;
                run = 0.0f;
            }
            run += vals[j][t];
        }
        atomicAdd(&gsum[curg * 64 + q * 16 + t], run);
    }
}

__global__ __launch_bounds__(128) void final_kernel(const float* __restrict__ gsum,
                                                    const float* __restrict__ gcnt,
                                                    const float* __restrict__ Wlin,
                                                    const float* __restrict__ blin,
                                                    float* __restrict__ out) {
    int t = threadIdx.x;  // 128 = G*C
    int g = t >> 1;
    int c = t & 1;
    float cnt = fmaxf(gcnt[g], 1.0f);
    float s = 0.0f;
#pragma unroll
    for (int k = 0; k < 64; k++) s = fmaf(gsum[g * 64 + k], Wlin[k * 2 + c], s);
    out[t] = s / cnt + blin[c];
}

extern "C" void kernel_launch(void* const* d_in, const int* in_sizes, int n_in,
                              void* d_out, int out_size, void* d_ws, size_t ws_size,
                              hipStream_t stream) {
    const float* x     = (const float*)d_in[0];
    const int*   ei    = (const int*)d_in[1];
    const int*   batch = (const int*)d_in[2];
    const float* W0    = (const float*)d_in[3];
    const float* b0    = (const float*)d_in[4];
    const float* W1    = (const float*)d_in[5];
    const float* b1    = (const float*)d_in[6];
    const float* W2    = (const float*)d_in[7];
    const float* b2    = (const float*)d_in[8];
    const float* Wlin  = (const float*)d_in[9];
    const float* blin  = (const float*)d_in[10];
    float* out = (float*)d_out;

    char* ws = (char*)d_ws;
    int*      rowStart = (int*)(ws + 0);
    int*      rowLen   = (int*)(ws + 400000);
    float*    dinv     = (float*)(ws + 800000);
    int*      srcs     = (int*)(ws + 1200000);
    __half*   u        = (__half*)(ws + 14012288);
    __half*   hb       = (__half*)(ws + 26812288);
    int*      tmp      = (int*)(ws + 26812288);   // overlaps hb; dead before agg0
    _Float16* x16      = (_Float16*)(ws + 39624576);
    _Float16* Wh       = (_Float16*)(ws + 52424576);  // 3 x 32768 B, ends 52522880
    float*    gsum     = (float*)(ws + 52522880);
    float*    gcnt     = (float*)(ws + 52539264);
    int*      bcur     = (int*)(ws + 52539520);

    // zero gsum+gcnt+bcur (contiguous, AFTER Wh's true end)
    hipMemsetAsync(ws + 52522880, 0, 18204, stream);

    // prep: cast x -> fp16, swizzle W into MFMA B-frag tables (hi/lo)
    cast_kernel<<<cdiv_h(NN * 16, 256), 256, 0, stream>>>(x, x16);
    wswz_kernel<<<3, 256, 0, stream>>>(W0, W1, W2, Wh);

    // CSR build: fixed-capacity bucket partition -> per-bucket sort
    bplace_kernel<<<cdiv_h(EE, 4096), 256, 0, stream>>>(ei, bcur, tmp);
    bsort_kernel<<<NBK, 256, 0, stream>>>(tmp, bcur, rowStart, rowLen, dinv, srcs);
    gcnt_kernel<<<NBK, 256, 0, stream>>>(batch, gcnt);

    int gemm_blocks = cdiv_h(NN / 16, 4);    // 6250 waves, 16 rows each
    int agg_blocks = (NN / 32) * 4;          // 3125 node-groups x 4 feature quarters

    gemm_mfma_kernel<<<gemm_blocks, 256, 0, stream>>>(x16, Wh, dinv, (_Float16*)u);
    agg_kernel<<<agg_blocks, 256, 0, stream>>>(u, srcs, rowStart, rowLen, dinv, b0, hb);
    gemm_mfma_kernel<<<gemm_blocks, 256, 0, stream>>>((const _Float16*)hb, Wh + 16384, dinv, (_Float16*)u);
    agg_kernel<<<agg_blocks, 256, 0, stream>>>(u, srcs, rowStart, rowLen, dinv, b1, hb);
    gemm_mfma_kernel<<<gemm_blocks, 256, 0, stream>>>((const _Float16*)hb, Wh + 32768, dinv, (_Float16*)u);
    agg_pool_kernel<<<agg_blocks, 256, 0, stream>>>(u, srcs, rowStart, rowLen, dinv, b2, batch, gsum);

    final_kernel<<<1, 128, 0, stream>>>(gsum, gcnt, Wlin, blin, out);
}

// Round 13
// 314.820 us; speedup vs baseline: 1.7172x; 1.0064x over previous
//
#include <hip/hip_runtime.h>
#include <hip/hip_fp16.h>

#define NN 100000
#define EE 1600000
#define HH 64
#define GG 64
#define NBK 391    // buckets of 256 nodes: dst>>8
#define CAP 8192   // fixed bucket capacity (mean load 4092, max ~4400)

typedef _Float16 f16x8 __attribute__((ext_vector_type(8)));
typedef _Float16 f16x4 __attribute__((ext_vector_type(4)));
typedef float f32x4 __attribute__((ext_vector_type(4)));

// ---------------- workspace layout (bytes) ----------------
// rowStart : int[NN]          @ 0
// rowLen   : int[NN]          @ 400000
// dinv     : float[NN]        @ 800000
// srcs     : int[NBK*CAP]     @ 1200000   (ends 14012288)
// u        : half[4][NN][16]  @ 14012288  (ends 26812288)
// hb(half) : half[NN*64]      @ 26812288  (ends 39612288)
// tmp      : int[NBK*CAP]     @ 26812288  (overlaps hb; dead before agg0; ends 39624576)
// x16      : half[NN*64]      @ 39624576  (ends 52424576)
// Wh       : half[3][16384]   @ 52424576  (32KB/layer, ends 52522880)
// gsum     : float[4096]      @ 52522880
// gcnt     : float[64]        @ 52539264
// bcur     : int[NBK]         @ 52539520

static inline int cdiv_h(int a, int b) { return (a + b - 1) / b; }

// ---- partition edges into fixed-capacity buckets (391 blocks x 4096 edges) ----
__global__ __launch_bounds__(256) void bplace_kernel(const int* __restrict__ ei,
                                                     int* __restrict__ bcur,
                                                     int* __restrict__ tmp) {
    __shared__ int h[NBK];
    __shared__ int boff[NBK];
    for (int t = threadIdx.x; t < NBK; t += 256) h[t] = 0;
    __syncthreads();
    int base = blockIdx.x * 4096;
#pragma unroll 4
    for (int i = 0; i < 16; i++) {
        int e = base + i * 256 + threadIdx.x;
        if (e < EE) atomicAdd(&h[ei[EE + e] >> 8], 1);
    }
    __syncthreads();
    for (int t = threadIdx.x; t < NBK; t += 256) {
        int c = h[t];
        boff[t] = c ? (t * CAP + atomicAdd(&bcur[t], c)) : 0;
        h[t] = 0;  // reuse as running cursor
    }
    __syncthreads();
#pragma unroll 4
    for (int i = 0; i < 16; i++) {
        int e = base + i * 256 + threadIdx.x;
        if (e < EE) {
            int s0 = ei[e];
            int d = ei[EE + e];
            int b = d >> 8;
            int p = boff[b] + atomicAdd(&h[b], 1);
            tmp[p] = (s0 << 8) | (d & 255);
        }
    }
}

// ---- per-bucket counting sort: srcs (bucket-strided CSR), rowStart/Len, dinv ----
__global__ __launch_bounds__(256) void bsort_kernel(const int* __restrict__ tmp,
                                                    const int* __restrict__ bcur,
                                                    int* __restrict__ rowStart,
                                                    int* __restrict__ rowLen,
                                                    float* __restrict__ dinv,
                                                    int* __restrict__ srcs) {
    int b = blockIdx.x;
    int n0 = b << 8;
    int e0 = b * CAP;
    int e1 = e0 + bcur[b];
    int t = threadIdx.x;
    __shared__ int cnt[256];
    __shared__ int st[256];
    cnt[t] = 0;
    __syncthreads();
    for (int e = e0 + t; e < e1; e += 256) atomicAdd(&cnt[tmp[e] & 255], 1);
    __syncthreads();
    int v = cnt[t];
    st[t] = v;
    __syncthreads();
    for (int off = 1; off < 256; off <<= 1) {
        int w = (t >= off) ? st[t - off] : 0;
        __syncthreads();
        st[t] += w;
        __syncthreads();
    }
    int excl = st[t] - v;
    int n = n0 + t;
    if (n < NN) {
        rowStart[n] = e0 + excl;
        rowLen[n] = v;
        dinv[n] = rsqrtf((float)v + 1.0f);
    }
    __syncthreads();
    cnt[t] = e0 + excl;  // absolute cursor
    __syncthreads();
    for (int e = e0 + t; e < e1; e += 256) {
        int p = tmp[e];
        int pos = atomicAdd(&cnt[p & 255], 1);
        srcs[pos] = p >> 8;
    }
}

// ---- gcnt: parallel LDS histogram over sorted batch ids ----
__global__ __launch_bounds__(256) void gcnt_kernel(const int* __restrict__ batch,
                                                   float* __restrict__ gcnt) {
    __shared__ int h[GG];
    if (threadIdx.x < GG) h[threadIdx.x] = 0;
    __syncthreads();
    int n = blockIdx.x * 256 + threadIdx.x;
    if (n < NN) atomicAdd(&h[batch[n]], 1);
    __syncthreads();
    if (threadIdx.x < GG && h[threadIdx.x])
        atomicAdd(&gcnt[threadIdx.x], (float)h[threadIdx.x]);
}

// ---- cast x (fp32) -> x16 (fp16) ----
__global__ __launch_bounds__(256) void cast_kernel(const float* __restrict__ x,
                                                   _Float16* __restrict__ x16) {
    int i = blockIdx.x * 256 + threadIdx.x;  // one float4 per thread
    if (i >= NN * 16) return;
    float4 v = ((const float4*)x)[i];
    f16x4 o = {(_Float16)v.x, (_Float16)v.y, (_Float16)v.z, (_Float16)v.w};
    ((f16x4*)x16)[i] = o;
}

// ---- swizzle W (fp32 row-major [k][n]) into MFMA B-frag order, hi/lo fp16 ----
// B-frag for mfma_f32_16x16x32_f16: lane holds B[k=(lane>>4)*8+j][n=lane&15].
// Table per layer: frag = (t*2+h)*2+p, offset = (frag*64+lane)*8+j. 32KB/layer.
__global__ __launch_bounds__(256) void wswz_kernel(const float* __restrict__ W0,
                                                   const float* __restrict__ W1,
                                                   const float* __restrict__ W2,
                                                   _Float16* __restrict__ Wh) {
    const float* Wl = (blockIdx.x == 0) ? W0 : (blockIdx.x == 1) ? W1 : W2;
    _Float16* out = Wh + blockIdx.x * 16384;
    for (int c = threadIdx.x; c < 512; c += 256) {  // t(4) x h(2) x lane(64)
        int t = c >> 7;
        int h = (c >> 6) & 1;
        int lane = c & 63;
        int quad = lane >> 4;
        int n = lane & 15;
#pragma unroll
        for (int j = 0; j < 8; j++) {
            int k = h * 32 + quad * 8 + j;
            float w = Wl[k * 64 + t * 16 + n];
            _Float16 hi = (_Float16)w;
            _Float16 lo = (_Float16)(w - (float)hi);
            out[(((t * 2 + h) * 2 + 0) * 64 + lane) * 8 + j] = hi;
            out[(((t * 2 + h) * 2 + 1) * 64 + lane) * 8 + j] = lo;
        }
    }
}

// ---- quarter-local MFMA gemm: u[q][stripe][:] computed on the XCD that will
// read it (q = blockIdx&3 matches agg's q->XCD mapping; R6/R7-confirmed).
// Wave = 16 rows x col-tile q: 2 A loads, 4 B frags, 4 MFMAs. A rows read 4x
// (once per quarter) -- streaming, latency-tolerant; u write is XCD-local.
__global__ __launch_bounds__(256) void gemm_mfma_kernel(const _Float16* __restrict__ hin,
                                                        const _Float16* __restrict__ Whl,
                                                        const float* __restrict__ dinv,
                                                        _Float16* __restrict__ u) {
    int q = blockIdx.x & 3;
    int stripe = (blockIdx.x >> 2) * 4 + (threadIdx.x >> 6);
    if (stripe >= NN / 16) return;
    int lane = threadIdx.x & 63;
    int m = lane & 15;
    int quad = lane >> 4;
    int n0 = stripe * 16;

    f16x8 a0 = *(const f16x8*)(hin + (size_t)(n0 + m) * 64 + quad * 8);
    f16x8 a1 = *(const f16x8*)(hin + (size_t)(n0 + m) * 64 + 32 + quad * 8);

    f16x8 bh0 = *(const f16x8*)(Whl + (((q * 2 + 0) * 2 + 0) * 64 + lane) * 8);
    f16x8 bl0 = *(const f16x8*)(Whl + (((q * 2 + 0) * 2 + 1) * 64 + lane) * 8);
    f16x8 bh1 = *(const f16x8*)(Whl + (((q * 2 + 1) * 2 + 0) * 64 + lane) * 8);
    f16x8 bl1 = *(const f16x8*)(Whl + (((q * 2 + 1) * 2 + 1) * 64 + lane) * 8);

    f32x4 acc = (f32x4){0.f, 0.f, 0.f, 0.f};
    acc = __builtin_amdgcn_mfma_f32_16x16x32_f16(a0, bh0, acc, 0, 0, 0);
    acc = __builtin_amdgcn_mfma_f32_16x16x32_f16(a0, bl0, acc, 0, 0, 0);
    acc = __builtin_amdgcn_mfma_f32_16x16x32_f16(a1, bh1, acc, 0, 0, 0);
    acc = __builtin_amdgcn_mfma_f32_16x16x32_f16(a1, bl1, acc, 0, 0, 0);

    // D layout: col = lane&15 (= m), row = quad*4 + reg  [m89/m91 measured]
    float4 dv4 = *(const float4*)(dinv + n0 + quad * 4);
    const float* dvp = (const float*)&dv4;
#pragma unroll
    for (int i = 0; i < 4; i++) {
        int n = n0 + quad * 4 + i;
        u[((size_t)q * NN + n) * 16 + m] = (_Float16)(acc[i] * dvp[i]);
    }
}

// ---- quarter gather: 2 lanes per edge-quarter, 16B loads, 8 nodes per wave ----
// lane = ng*8 + sub*2 + fl : ng = node (8/wave), sub = edge slot (4), fl = half-row.
__device__ __forceinline__ void add8(float4 raw, float* a) {
    const __half2* h = (const __half2*)&raw;
#pragma unroll
    for (int i = 0; i < 4; i++) {
        float2 f = __half22float2(h[i]);
        a[2 * i] += f.x;
        a[2 * i + 1] += f.y;
    }
}

__device__ __forceinline__ void gatherq8(const __half* __restrict__ uq,
                                         const int* __restrict__ srcs,
                                         int n, int sub, int fl, int rs, int len,
                                         float* a) {
#pragma unroll
    for (int i = 0; i < 8; i++) a[i] = 0.0f;
    if (sub == 0)
        add8(*(const float4*)(uq + (size_t)n * 16 + fl * 8), a);
    int e = rs + sub, end = rs + len;
    for (; e + 4 < end; e += 8) {
        int sA = srcs[e];
        int sB = srcs[e + 4];
        float4 ra = *(const float4*)(uq + (size_t)sA * 16 + fl * 8);
        float4 rb = *(const float4*)(uq + (size_t)sB * 16 + fl * 8);
        add8(ra, a);
        add8(rb, a);
    }
    if (e < end)
        add8(*(const float4*)(uq + (size_t)srcs[e] * 16 + fl * 8), a);
}

__device__ __forceinline__ void sub_reduce8(float* a) {
#pragma unroll
    for (int m = 2; m <= 4; m <<= 1) {
#pragma unroll
        for (int i = 0; i < 8; i++) a[i] += __shfl_xor(a[i], m);
    }
}

__device__ __forceinline__ void relu_bias8(const float* a, float dv,
                                           const float* bias_p, float* r) {
    const float4* bb = (const float4*)bias_p;
    float4 b0 = bb[0], b1 = bb[1];
    r[0] = fmaxf(fmaf(dv, a[0], b0.x), 0.0f);
    r[1] = fmaxf(fmaf(dv, a[1], b0.y), 0.0f);
    r[2] = fmaxf(fmaf(dv, a[2], b0.z), 0.0f);
    r[3] = fmaxf(fmaf(dv, a[3], b0.w), 0.0f);
    r[4] = fmaxf(fmaf(dv, a[4], b1.x), 0.0f);
    r[5] = fmaxf(fmaf(dv, a[5], b1.y), 0.0f);
    r[6] = fmaxf(fmaf(dv, a[6], b1.z), 0.0f);
    r[7] = fmaxf(fmaf(dv, a[7], b1.w), 0.0f);
}

// layers 0,1: block = 32 nodes x 1 quarter; q = blockIdx&3. fp16 out.
__global__ __launch_bounds__(256) void agg_kernel(const __half* __restrict__ u,
                                                  const int* __restrict__ srcs,
                                                  const int* __restrict__ rowStart,
                                                  const int* __restrict__ rowLen,
                                                  const float* __restrict__ dinv,
                                                  const float* __restrict__ bias,
                                                  __half* __restrict__ hout) {
    int q = blockIdx.x & 3;
    int grp = blockIdx.x >> 2;
    int w = threadIdx.x >> 6;
    int lane = threadIdx.x & 63;
    int ng = lane >> 3;
    int sub = (lane >> 1) & 3;
    int fl = lane & 1;
    int n = grp * 32 + w * 8 + ng;
    const __half* uq = u + (size_t)q * NN * 16;
    int rs = rowStart[n], len = rowLen[n];
    float a[8];
    gatherq8(uq, srcs, n, sub, fl, rs, len, a);
    sub_reduce8(a);
    if (sub == 0) {
        float r[8];
        relu_bias8(a, dinv[n], bias + q * 16 + fl * 8, r);
        __half2 hh[4];
#pragma unroll
        for (int i = 0; i < 4; i++) hh[i] = __floats2half2_rn(r[2 * i], r[2 * i + 1]);
        *(float4*)(hout + (size_t)n * 64 + q * 16 + fl * 8) = *(float4*)hh;
    }
}

// layer 2 fused with mean-pool partial sums (32 nodes x 1 quarter per block)
__global__ __launch_bounds__(256) void agg_pool_kernel(const __half* __restrict__ u,
                                                       const int* __restrict__ srcs,
                                                       const int* __restrict__ rowStart,
                                                       const int* __restrict__ rowLen,
                                                       const float* __restrict__ dinv,
                                                       const float* __restrict__ bias,
                                                       const int* __restrict__ batch,
                                                       float* __restrict__ gsum) {
    int q = blockIdx.x & 3;
    int grp = blockIdx.x >> 2;
    int w = threadIdx.x >> 6;
    int lane = threadIdx.x & 63;
    int ng = lane >> 3;
    int sub = (lane >> 1) & 3;
    int fl = lane & 1;
    int n = grp * 32 + w * 8 + ng;
    const __half* uq = u + (size_t)q * NN * 16;
    __shared__ float vals[32][16];
    __shared__ int gid[32];
    int rs = rowStart[n], len = rowLen[n];
    float a[8];
    gatherq8(uq, srcs, n, sub, fl, rs, len, a);
    sub_reduce8(a);
    if (sub == 0) {
        float r[8];
        relu_bias8(a, dinv[n], bias + q * 16 + fl * 8, r);
        float4* vp = (float4*)(&vals[w * 8 + ng][fl * 8]);
        vp[0] = make_float4(r[0], r[1], r[2], r[3]);
        vp[1] = make_float4(r[4], r[5], r[6], r[7]);
    }
    if ((lane & 7) == 0) gid[w * 8 + ng] = batch[n];
    __syncthreads();
    if (threadIdx.x < 16) {
        int t = threadIdx.x;
        float run = vals[0][t];
        int curg = gid[0];
        for (int j = 1; j < 32; j++) {
            int gj = gid[j];
            if (gj != curg) {
                atomicAdd(&gsum[curg * 64 + q * 16 + t], run);
                curg = gj;
                run = 0.0f;
            }
            run += vals[j][t];
        }
        atomicAdd(&gsum[curg * 64 + q * 16 + t], run);
    }
}

__global__ __launch_bounds__(128) void final_kernel(const float* __restrict__ gsum,
                                                    const float* __restrict__ gcnt,
                                                    const float* __restrict__ Wlin,
                                                    const float* __restrict__ blin,
                                                    float* __restrict__ out) {
    int t = threadIdx.x;  // 128 = G*C
    int g = t >> 1;
    int c = t & 1;
    float cnt = fmaxf(gcnt[g], 1.0f);
    float s = 0.0f;
#pragma unroll
    for (int k = 0; k < 64; k++) s = fmaf(gsum[g * 64 + k], Wlin[k * 2 + c], s);
    out[t] = s / cnt + blin[c];
}

extern "C" void kernel_launch(void* const* d_in, const int* in_sizes, int n_in,
                              void* d_out, int out_size, void* d_ws, size_t ws_size,
                              hipStream_t stream) {
    const float* x     = (const float*)d_in[0];
    const int*   ei    = (const int*)d_in[1];
    const int*   batch = (const int*)d_in[2];
    const float* W0    = (const float*)d_in[3];
    const float* b0    = (const float*)d_in[4];
    const float* W1    = (const float*)d_in[5];
    const float* b1    = (const float*)d_in[6];
    const float* W2    = (const float*)d_in[7];
    const float* b2    = (const float*)d_in[8];
    const float* Wlin  = (const float*)d_in[9];
    const float* blin  = (const float*)d_in[10];
    float* out = (float*)d_out;

    char* ws = (char*)d_ws;
    int*      rowStart = (int*)(ws + 0);
    int*      rowLen   = (int*)(ws + 400000);
    float*    dinv     = (float*)(ws + 800000);
    int*      srcs     = (int*)(ws + 1200000);
    __half*   u        = (__half*)(ws + 14012288);
    __half*   hb       = (__half*)(ws + 26812288);
    int*      tmp      = (int*)(ws + 26812288);   // overlaps hb; dead before agg0
    _Float16* x16      = (_Float16*)(ws + 39624576);
    _Float16* Wh       = (_Float16*)(ws + 52424576);  // 3 x 32768 B, ends 52522880
    float*    gsum     = (float*)(ws + 52522880);
    float*    gcnt     = (float*)(ws + 52539264);
    int*      bcur     = (int*)(ws + 52539520);

    // zero gsum+gcnt+bcur (contiguous, after Wh's end)
    hipMemsetAsync(ws + 52522880, 0, 18204, stream);

    // prep: cast x -> fp16, swizzle W into MFMA B-frag tables (hi/lo)
    cast_kernel<<<cdiv_h(NN * 16, 256), 256, 0, stream>>>(x, x16);
    wswz_kernel<<<3, 256, 0, stream>>>(W0, W1, W2, Wh);

    // CSR build: fixed-capacity bucket partition -> per-bucket sort
    bplace_kernel<<<cdiv_h(EE, 4096), 256, 0, stream>>>(ei, bcur, tmp);
    bsort_kernel<<<NBK, 256, 0, stream>>>(tmp, bcur, rowStart, rowLen, dinv, srcs);
    gcnt_kernel<<<NBK, 256, 0, stream>>>(batch, gcnt);

    int gemm_blocks = cdiv_h(NN / 16, 4) * 4;  // 1563 stripe-groups x 4 quarters
    int agg_blocks = (NN / 32) * 4;            // 3125 node-groups x 4 quarters

    gemm_mfma_kernel<<<gemm_blocks, 256, 0, stream>>>(x16, Wh, dinv, (_Float16*)u);
    agg_kernel<<<agg_blocks, 256, 0, stream>>>(u, srcs, rowStart, rowLen, dinv, b0, hb);
    gemm_mfma_kernel<<<gemm_blocks, 256, 0, stream>>>((const _Float16*)hb, Wh + 16384, dinv, (_Float16*)u);
    agg_kernel<<<agg_blocks, 256, 0, stream>>>(u, srcs, rowStart, rowLen, dinv, b1, hb);
    gemm_mfma_kernel<<<gemm_blocks, 256, 0, stream>>>((const _Float16*)hb, Wh + 32768, dinv, (_Float16*)u);
    agg_pool_kernel<<<agg_blocks, 256, 0, stream>>>(u, srcs, rowStart, rowLen, dinv, b2, batch, gsum);

    final_kernel<<<1, 128, 0, stream>>>(gsum, gcnt, Wlin, blin, out);
}